// Round 2
// baseline (7263.777 us; speedup 1.0000x reference)
//
#include <hip/hip_runtime.h>
#include <stdint.h>

typedef short s16x8 __attribute__((ext_vector_type(8)));
typedef float f32x4 __attribute__((ext_vector_type(4)));

#define LSEG 511
#define BT 16

static __device__ __forceinline__ unsigned short f2bf(float f) {
  union { float f; uint32_t u; } v; v.f = f;
  uint32_t r = (v.u + 0x7FFFu + ((v.u >> 16) & 1u)) >> 16;
  return (unsigned short)r;
}
static __device__ __forceinline__ float tanh_fast(float x) {
  float ex = __expf(2.f * x);
  return 1.f - 2.f * __builtin_amdgcn_rcpf(ex + 1.f);
}

// 16 batch rows per block, 8 waves (512 thr). Weights in per-wave register
// fragments. Per RK stage only 4 barriers:
//   [A: zz-in-reg + L1] [L2] [L3] [L4 + einsum-in-reg + k-write]
// f (16x512) never touches LDS; z/k stay fp32 in LDS; dX precomputed per
// segment from registers prefetched one segment ahead.
__global__ __launch_bounds__(512, 2) void cde_kernel(
    const float* __restrict__ coeffs,
    const float* __restrict__ W_init, const float* __restrict__ b_init,
    const float* __restrict__ W_in,  const float* __restrict__ b_in,
    const float* __restrict__ W_h,   const float* __restrict__ b_h,
    const float* __restrict__ W_out, const float* __restrict__ b_out,
    const float* __restrict__ W_read,const float* __restrict__ b_read,
    float* __restrict__ out)
{
  __shared__ unsigned short hA[16][136];   // 272B row stride, 16B aligned
  __shared__ unsigned short hB[16][136];
  __shared__ float zbuf[2][16][68];        // 272B stride
  __shared__ float kbuf[4][16][68];
  __shared__ float dxb[4][16][9];

  const int tid  = threadIdx.x;
  const int w    = tid >> 6;     // wave 0..7
  const int lane = tid & 63;
  const int lr   = lane & 15;
  const int lk   = lane >> 4;
  const int b0   = blockIdx.x * BT;

  // ---- weight fragments (MFMA B layout: elem e = W[32*kq+8*lk+e][col]) ----
  s16x8 Win_f[2], Wh0_f[4], Wh1_f[4], Wout_f[4][4];
  const int wc = 16*w + lr;                // L1-3 col for this wave/lane
  #pragma unroll
  for (int kq = 0; kq < 2; ++kq)
    #pragma unroll
    for (int e = 0; e < 8; ++e)
      Win_f[kq][e] = (short)f2bf(W_in[(32*kq + 8*lk + e)*128 + wc]);
  #pragma unroll
  for (int kq = 0; kq < 4; ++kq)
    #pragma unroll
    for (int e = 0; e < 8; ++e) {
      Wh0_f[kq][e] = (short)f2bf(W_h[(32*kq + 8*lk + e)*128 + wc]);
      Wh1_f[kq][e] = (short)f2bf(W_h[16384 + (32*kq + 8*lk + e)*128 + wc]);
    }
  #pragma unroll
  for (int kq = 0; kq < 4; ++kq)
    #pragma unroll
    for (int nt = 0; nt < 4; ++nt)
      #pragma unroll
      for (int e = 0; e < 8; ++e)
        Wout_f[kq][nt][e] = (short)f2bf(W_out[(32*kq + 8*lk + e)*512 + 64*w + 16*nt + lr]);
  const float bin = b_in[wc];
  const float bh0 = b_h[wc];
  const float bh1 = b_h[128 + wc];
  float bout[4];
  #pragma unroll
  for (int nt = 0; nt < 4; ++nt) bout[nt] = b_out[64*w + 16*nt + lr];

  // ---- init: z0 = a[:,0,:] @ W_init + b_init ; kbuf = 0 ----
  {
    const int row = tid >> 5, h2 = (tid & 31) * 2;
    const float* a0 = &coeffs[(size_t)(b0 + row) * (LSEG * 32)];
    float s0 = b_init[h2], s1 = b_init[h2 + 1];
    #pragma unroll
    for (int c = 0; c < 8; ++c) {
      float a = a0[c];
      s0 += a * W_init[c*64 + h2];
      s1 += a * W_init[c*64 + h2 + 1];
    }
    zbuf[0][row][h2]   = s0;
    zbuf[0][row][h2+1] = s1;
  }
  for (int i = tid; i < 4*16*68; i += 512) ((float*)kbuf)[i] = 0.f;

  // coeff regs for segment 0 (b, two_c, three_d at col dxc of row dxrow)
  float cf_b = 0.f, cf_c = 0.f, cf_d = 0.f;
  const int dxrow = tid >> 3, dxc = tid & 7;
  if (tid < 128) {
    const float* cp = &coeffs[(size_t)(b0 + dxrow) * (LSEG * 32)];
    cf_b = cp[8 + dxc]; cf_c = cp[16 + dxc]; cf_d = cp[24 + dxc];
  }
  __syncthreads();

  for (int t = 0; t < LSEG; ++t) {
    const int p = t & 1;
    #pragma unroll
    for (int s = 0; s < 4; ++s) {
      // ================= Phase A: dX (s==0), zz in-reg, L1 =================
      if (s == 0 && tid < 128) {
        dxb[0][dxrow][dxc] = cf_b;
        dxb[1][dxrow][dxc] = cf_b + (cf_c + cf_d*(1.f/3.f))*(1.f/3.f);
        dxb[2][dxrow][dxc] = cf_b + (cf_c + cf_d*(2.f/3.f))*(2.f/3.f);
        dxb[3][dxrow][dxc] = cf_b + cf_c + cf_d;
        if (t + 1 < LSEG) {  // prefetch next segment's coeffs
          const float* cp = &coeffs[((size_t)(b0 + dxrow) * LSEG + (t + 1)) * 32];
          cf_b = cp[8 + dxc]; cf_c = cp[16 + dxc]; cf_d = cp[24 + dxc];
        }
      }
      {
        const int q = (s == 0) ? p : (p ^ 1);
        const float* zr = &zbuf[q][lr][0];
        const int c0 = 8 * lk, c1 = 32 + 8 * lk;
        f32x4 v0 = *(const f32x4*)(zr + c0);
        f32x4 v1 = *(const f32x4*)(zr + c0 + 4);
        f32x4 v2 = *(const f32x4*)(zr + c1);
        f32x4 v3 = *(const f32x4*)(zr + c1 + 4);
        const float* k0 = &kbuf[0][lr][0];
        const float* k1 = &kbuf[1][lr][0];
        const float* k2 = &kbuf[2][lr][0];
        const float* k3 = &kbuf[3][lr][0];
        const float third = 1.f / 3.f;
        if (s == 0) {
          // z_new = z + (k1 + 3(k2+k3) + k4)/8  (prev segment's k; zeros at t=0)
          v0 += 0.125f * (*(const f32x4*)(k0+c0)   + 3.f*(*(const f32x4*)(k1+c0)   + *(const f32x4*)(k2+c0))   + *(const f32x4*)(k3+c0));
          v1 += 0.125f * (*(const f32x4*)(k0+c0+4) + 3.f*(*(const f32x4*)(k1+c0+4) + *(const f32x4*)(k2+c0+4)) + *(const f32x4*)(k3+c0+4));
          v2 += 0.125f * (*(const f32x4*)(k0+c1)   + 3.f*(*(const f32x4*)(k1+c1)   + *(const f32x4*)(k2+c1))   + *(const f32x4*)(k3+c1));
          v3 += 0.125f * (*(const f32x4*)(k0+c1+4) + 3.f*(*(const f32x4*)(k1+c1+4) + *(const f32x4*)(k2+c1+4)) + *(const f32x4*)(k3+c1+4));
          if (w == 0) {  // materialize z for stages 1..3 and next segment
            float* zw = &zbuf[p ^ 1][lr][0];
            *(f32x4*)(zw + c0)     = v0;
            *(f32x4*)(zw + c0 + 4) = v1;
            *(f32x4*)(zw + c1)     = v2;
            *(f32x4*)(zw + c1 + 4) = v3;
          }
        } else if (s == 1) {
          v0 += third * *(const f32x4*)(k0+c0);
          v1 += third * *(const f32x4*)(k0+c0+4);
          v2 += third * *(const f32x4*)(k0+c1);
          v3 += third * *(const f32x4*)(k0+c1+4);
        } else if (s == 2) {
          v0 += *(const f32x4*)(k1+c0)   - third * *(const f32x4*)(k0+c0);
          v1 += *(const f32x4*)(k1+c0+4) - third * *(const f32x4*)(k0+c0+4);
          v2 += *(const f32x4*)(k1+c1)   - third * *(const f32x4*)(k0+c1);
          v3 += *(const f32x4*)(k1+c1+4) - third * *(const f32x4*)(k0+c1+4);
        } else {
          v0 += *(const f32x4*)(k0+c0)   - *(const f32x4*)(k1+c0)   + *(const f32x4*)(k2+c0);
          v1 += *(const f32x4*)(k0+c0+4) - *(const f32x4*)(k1+c0+4) + *(const f32x4*)(k2+c0+4);
          v2 += *(const f32x4*)(k0+c1)   - *(const f32x4*)(k1+c1)   + *(const f32x4*)(k2+c1);
          v3 += *(const f32x4*)(k0+c1+4) - *(const f32x4*)(k1+c1+4) + *(const f32x4*)(k2+c1+4);
        }
        s16x8 af0, af1;  // A frags: row=lr, k=32*kq+8*lk+e
        #pragma unroll
        for (int e = 0; e < 4; ++e) {
          af0[e]     = (short)f2bf(v0[e]);
          af0[4 + e] = (short)f2bf(v1[e]);
          af1[e]     = (short)f2bf(v2[e]);
          af1[4 + e] = (short)f2bf(v3[e]);
        }
        f32x4 acc = {};
        acc = __builtin_amdgcn_mfma_f32_16x16x32_bf16(af0, Win_f[0], acc, 0, 0, 0);
        acc = __builtin_amdgcn_mfma_f32_16x16x32_bf16(af1, Win_f[1], acc, 0, 0, 0);
        #pragma unroll
        for (int r = 0; r < 4; ++r)
          hA[4*lk + r][wc] = f2bf(fmaxf(acc[r] + bin, 0.f));
      }
      __syncthreads();

      // ================= L2: hA @ Wh0 -> hB =================
      {
        s16x8 a[4];
        #pragma unroll
        for (int kq = 0; kq < 4; ++kq)
          a[kq] = *(const s16x8*)&hA[lr][32*kq + 8*lk];
        f32x4 acc = {};
        #pragma unroll
        for (int kq = 0; kq < 4; ++kq)
          acc = __builtin_amdgcn_mfma_f32_16x16x32_bf16(a[kq], Wh0_f[kq], acc, 0, 0, 0);
        #pragma unroll
        for (int r = 0; r < 4; ++r)
          hB[4*lk + r][wc] = f2bf(fmaxf(acc[r] + bh0, 0.f));
      }
      __syncthreads();

      // ================= L3: hB @ Wh1 -> hA =================
      {
        s16x8 a[4];
        #pragma unroll
        for (int kq = 0; kq < 4; ++kq)
          a[kq] = *(const s16x8*)&hB[lr][32*kq + 8*lk];
        f32x4 acc = {};
        #pragma unroll
        for (int kq = 0; kq < 4; ++kq)
          acc = __builtin_amdgcn_mfma_f32_16x16x32_bf16(a[kq], Wh1_f[kq], acc, 0, 0, 0);
        #pragma unroll
        for (int r = 0; r < 4; ++r)
          hA[4*lk + r][wc] = f2bf(fmaxf(acc[r] + bh1, 0.f));
      }
      __syncthreads();

      // ====== L4: hA @ W_out, tanh, einsum with dX via 8-lane butterfly ======
      {
        s16x8 a[4];
        #pragma unroll
        for (int kq = 0; kq < 4; ++kq)
          a[kq] = *(const s16x8*)&hA[lr][32*kq + 8*lk];
        f32x4 acc[4] = {};
        #pragma unroll
        for (int kq = 0; kq < 4; ++kq)
          #pragma unroll
          for (int nt = 0; nt < 4; ++nt)
            acc[nt] = __builtin_amdgcn_mfma_f32_16x16x32_bf16(a[kq], Wout_f[kq][nt], acc[nt], 0, 0, 0);
        float dxv[4];
        #pragma unroll
        for (int r = 0; r < 4; ++r)
          dxv[r] = dxb[s][4*lk + r][lane & 7];   // c = lane&7
        // col = 64w+16nt+lr  ->  h = 8w+2nt+(lr>>3), c = lr&7
        #pragma unroll
        for (int nt = 0; nt < 4; ++nt) {
          #pragma unroll
          for (int r = 0; r < 4; ++r) {
            float v = tanh_fast(acc[nt][r] + bout[nt]) * dxv[r];
            v += __shfl_xor(v, 1);
            v += __shfl_xor(v, 2);
            v += __shfl_xor(v, 4);
            if ((lane & 7) == 0)
              kbuf[s][4*lk + r][8*w + 2*nt + ((lane >> 3) & 1)] = v;
          }
        }
      }
      __syncthreads();
    }
  }

  // ---- readout: z_final = zbuf[1] + combo(kbuf of segment 510) ----
  if (tid < BT) {
    float acc = b_read[0];
    #pragma unroll 8
    for (int h = 0; h < 64; ++h) {
      float zf = zbuf[1][tid][h] + 0.125f * (kbuf[0][tid][h]
               + 3.f * (kbuf[1][tid][h] + kbuf[2][tid][h]) + kbuf[3][tid][h]);
      acc += zf * W_read[h];
    }
    out[b0 + tid] = acc;
  }
}

extern "C" void kernel_launch(void* const* d_in, const int* in_sizes, int n_in,
                              void* d_out, int out_size, void* d_ws, size_t ws_size,
                              hipStream_t stream) {
  const float* coeffs = (const float*)d_in[0];
  const float* W_init = (const float*)d_in[1];
  const float* b_init = (const float*)d_in[2];
  const float* W_in   = (const float*)d_in[3];
  const float* b_in   = (const float*)d_in[4];
  const float* W_h    = (const float*)d_in[5];
  const float* b_h    = (const float*)d_in[6];
  const float* W_out  = (const float*)d_in[7];
  const float* b_out  = (const float*)d_in[8];
  const float* W_read = (const float*)d_in[9];
  const float* b_read = (const float*)d_in[10];
  float* out = (float*)d_out;

  cde_kernel<<<dim3(4096 / BT), dim3(512), 0, stream>>>(
      coeffs, W_init, b_init, W_in, b_in, W_h, b_h, W_out, b_out,
      W_read, b_read, out);
}

// Round 3
// 4342.120 us; speedup vs baseline: 1.6729x; 1.6729x over previous
//
#include <hip/hip_runtime.h>
#include <stdint.h>

typedef short s16x8 __attribute__((ext_vector_type(8)));
typedef float f32x4 __attribute__((ext_vector_type(4)));

#define LSEG 511

static __device__ __forceinline__ uint32_t cvt_pk_bf16(float lo, float hi) {
  uint32_t r;
  asm("v_cvt_pk_bf16_f32 %0, %1, %2" : "=v"(r) : "v"(lo), "v"(hi));
  return r;
}
static __device__ __forceinline__ unsigned short f2bf(float f) {
  union { float f; uint32_t u; } v; v.f = f;
  uint32_t r = (v.u + 0x7FFFu + ((v.u >> 16) & 1u)) >> 16;
  return (unsigned short)r;
}
static __device__ __forceinline__ float tanh_fast(float x) {
  float ex = __expf(2.f * x);
  return 1.f - 2.f * __builtin_amdgcn_rcpf(ex + 1.f);
}

// 16 batch rows/block, 8 waves. Weights in registers (104 VGPR/wave).
// Per RK stage: 4 phases, 4 barriers. RK state (z0, zfin, k1, k2) lives in
// the einsum-holder lanes' registers via a c-major W_out column permutation
// (channel = 64w + 8*(lr&7) + 2*nt + (lr>>3)) so each lane's acc[nt] are 4
// c's of one h: einsum = 4 in-lane FMA + one shfl_xor(8). No fp32 state in
// LDS; activations ping-pong X -> H1 -> H2 -> H1 as bf16 with pair-packed
// cvt_pk writes (2-way conflict-free).
__global__ __launch_bounds__(512, 2) void cde_kernel(
    const float* __restrict__ coeffs,
    const float* __restrict__ W_init, const float* __restrict__ b_init,
    const float* __restrict__ W_in,  const float* __restrict__ b_in,
    const float* __restrict__ W_h,   const float* __restrict__ b_h,
    const float* __restrict__ W_out, const float* __restrict__ b_out,
    const float* __restrict__ W_read,const float* __restrict__ b_read,
    float* __restrict__ out)
{
  __shared__ unsigned short X[16][72];    // 144B stride (36 dw = 4 mod 32)
  __shared__ unsigned short H1[16][136];  // 272B stride (68 dw = 4 mod 32)
  __shared__ unsigned short H2[16][136];
  __shared__ float dx2[4][2][16][4];      // [s][hp][row][nt], c = 2*nt+hp

  const int tid  = threadIdx.x;
  const int w    = tid >> 6;     // wave 0..7
  const int lane = tid & 63;
  const int lr   = lane & 15;
  const int lk   = lane >> 4;
  const int lc   = lr & 7;
  const int hp   = lr >> 3;
  const int b0   = blockIdx.x * 16;
  const int h_own = 8*w + lc;    // this lane's h in the einsum

  // ---- weight fragments (B layout: elem e = W[32*kq+8*lk+e][col]) ----
  s16x8 Win_f[2], Wh0_f[4], Wh1_f[4], Wout_f[4][4];
  const int wc = 16*w + lr;      // L1-3 col
  #pragma unroll
  for (int kq = 0; kq < 2; ++kq)
    #pragma unroll
    for (int e = 0; e < 8; ++e)
      Win_f[kq][e] = (short)f2bf(W_in[(32*kq + 8*lk + e)*128 + wc]);
  #pragma unroll
  for (int kq = 0; kq < 4; ++kq)
    #pragma unroll
    for (int e = 0; e < 8; ++e) {
      Wh0_f[kq][e] = (short)f2bf(W_h[(32*kq + 8*lk + e)*128 + wc]);
      Wh1_f[kq][e] = (short)f2bf(W_h[16384 + (32*kq + 8*lk + e)*128 + wc]);
    }
  #pragma unroll
  for (int kq = 0; kq < 4; ++kq)
    #pragma unroll
    for (int nt = 0; nt < 4; ++nt) {
      const int ch = 64*w + 8*lc + 2*nt + hp;   // c-major permutation
      #pragma unroll
      for (int e = 0; e < 8; ++e)
        Wout_f[kq][nt][e] = (short)f2bf(W_out[(32*kq + 8*lk + e)*512 + ch]);
    }
  const float bin  = b_in[wc];
  const float bh0v = b_h[wc];
  const float bh1v = b_h[128 + wc];
  float bout[4];
  #pragma unroll
  for (int nt = 0; nt < 4; ++nt) bout[nt] = b_out[64*w + 8*lc + 2*nt + hp];

  // ---- z0 init (per-lane registers, 4 rows x 1 h each) ----
  float z0[4], zfin[4], k1r[4], k2r[4];
  {
    float Wi[8];
    #pragma unroll
    for (int c = 0; c < 8; ++c) Wi[c] = W_init[c*64 + h_own];
    const float bi = b_init[h_own];
    #pragma unroll
    for (int r = 0; r < 4; ++r) {
      const float* a0r = &coeffs[(size_t)(b0 + 4*lk + r) * (LSEG*32)];
      float s = bi;
      #pragma unroll
      for (int c = 0; c < 8; ++c) s = fmaf(a0r[c], Wi[c], s);
      z0[r] = s; zfin[r] = 0.f; k1r[r] = 0.f; k2r[r] = 0.f;
    }
    #pragma unroll
    for (int r = 0; r < 4; ++r) {   // X = bf16(z0)
      float p = __shfl_xor(z0[r], 1);
      if ((lr & 9) == 0)   // lc even, hp==0
        *(uint32_t*)&X[4*lk + r][8*w + lc] = cvt_pk_bf16(z0[r], p);
    }
  }

  // coeff regs for segment 0
  float cf_b = 0.f, cf_c = 0.f, cf_d = 0.f;
  const int crow = tid >> 3, cc = tid & 7;
  if (tid < 128) {
    const float* cp = &coeffs[(size_t)(b0 + crow)*(LSEG*32)];
    cf_b = cp[8+cc]; cf_c = cp[16+cc]; cf_d = cp[24+cc];
  }
  __syncthreads();

  for (int t = 0; t < LSEG; ++t) {
    #pragma unroll
    for (int s = 0; s < 4; ++s) {
      // =============== P1: (dx2 @ s==0) + L1: X -> H1 ===============
      if (s == 0 && tid < 128) {
        const float third = 1.f/3.f, two3 = 2.f/3.f;
        dx2[0][cc&1][crow][cc>>1] = cf_b;
        dx2[1][cc&1][crow][cc>>1] = fmaf(fmaf(cf_d, third, cf_c), third, cf_b);
        dx2[2][cc&1][crow][cc>>1] = fmaf(fmaf(cf_d, two3, cf_c), two3, cf_b);
        dx2[3][cc&1][crow][cc>>1] = cf_b + cf_c + cf_d;
        if (t + 1 < LSEG) {
          const float* cp = &coeffs[((size_t)(b0 + crow)*LSEG + (t+1))*32];
          cf_b = cp[8+cc]; cf_c = cp[16+cc]; cf_d = cp[24+cc];
        }
      }
      {
        s16x8 a0 = *(const s16x8*)&X[lr][8*lk];
        s16x8 a1 = *(const s16x8*)&X[lr][32 + 8*lk];
        f32x4 acc = {};
        acc = __builtin_amdgcn_mfma_f32_16x16x32_bf16(a0, Win_f[0], acc, 0, 0, 0);
        acc = __builtin_amdgcn_mfma_f32_16x16x32_bf16(a1, Win_f[1], acc, 0, 0, 0);
        #pragma unroll
        for (int r = 0; r < 4; ++r) {
          float v = fmaxf(acc[r] + bin, 0.f);
          float p = __shfl_xor(v, 1);
          if ((lr & 1) == 0)
            *(uint32_t*)&H1[4*lk + r][wc] = cvt_pk_bf16(v, p);
        }
      }
      __syncthreads();

      // =============== P2: L2: H1 -> H2 ===============
      {
        s16x8 a[4];
        #pragma unroll
        for (int kq = 0; kq < 4; ++kq)
          a[kq] = *(const s16x8*)&H1[lr][32*kq + 8*lk];
        f32x4 acc = {};
        #pragma unroll
        for (int kq = 0; kq < 4; ++kq)
          acc = __builtin_amdgcn_mfma_f32_16x16x32_bf16(a[kq], Wh0_f[kq], acc, 0, 0, 0);
        #pragma unroll
        for (int r = 0; r < 4; ++r) {
          float v = fmaxf(acc[r] + bh0v, 0.f);
          float p = __shfl_xor(v, 1);
          if ((lr & 1) == 0)
            *(uint32_t*)&H2[4*lk + r][wc] = cvt_pk_bf16(v, p);
        }
      }
      __syncthreads();

      // =============== P3: L3: H2 -> H1 ===============
      {
        s16x8 a[4];
        #pragma unroll
        for (int kq = 0; kq < 4; ++kq)
          a[kq] = *(const s16x8*)&H2[lr][32*kq + 8*lk];
        f32x4 acc = {};
        #pragma unroll
        for (int kq = 0; kq < 4; ++kq)
          acc = __builtin_amdgcn_mfma_f32_16x16x32_bf16(a[kq], Wh1_f[kq], acc, 0, 0, 0);
        #pragma unroll
        for (int r = 0; r < 4; ++r) {
          float v = fmaxf(acc[r] + bh1v, 0.f);
          float p = __shfl_xor(v, 1);
          if ((lr & 1) == 0)
            *(uint32_t*)&H1[4*lk + r][wc] = cvt_pk_bf16(v, p);
        }
      }
      __syncthreads();

      // ========= P4: L4 + tanh + einsum + RK state + X write =========
      {
        s16x8 a[4];
        #pragma unroll
        for (int kq = 0; kq < 4; ++kq)
          a[kq] = *(const s16x8*)&H1[lr][32*kq + 8*lk];
        f32x4 acc[4] = {};
        #pragma unroll
        for (int kq = 0; kq < 4; ++kq)
          #pragma unroll
          for (int nt = 0; nt < 4; ++nt)
            acc[nt] = __builtin_amdgcn_mfma_f32_16x16x32_bf16(a[kq], Wout_f[kq][nt], acc[nt], 0, 0, 0);
        #pragma unroll
        for (int r = 0; r < 4; ++r) {
          f32x4 dxv = *(const f32x4*)&dx2[s][hp][4*lk + r][0];
          float sum = 0.f;
          #pragma unroll
          for (int nt = 0; nt < 4; ++nt)
            sum = fmaf(tanh_fast(acc[nt][r] + bout[nt]), dxv[nt], sum);
          sum += __shfl_xor(sum, 8);   // add hp-complement: full c-sum
          float znext;
          if (s == 0) {
            k1r[r] = sum;
            zfin[r] = fmaf(0.125f, sum, z0[r]);
            znext   = fmaf(1.f/3.f, sum, z0[r]);
          } else if (s == 1) {
            k2r[r] = sum;
            zfin[r] = fmaf(0.375f, sum, zfin[r]);
            znext   = z0[r] + sum - (1.f/3.f)*k1r[r];
          } else if (s == 2) {
            zfin[r] = fmaf(0.375f, sum, zfin[r]);
            znext   = z0[r] + k1r[r] - k2r[r] + sum;
          } else {
            zfin[r] = fmaf(0.125f, sum, zfin[r]);
            znext   = zfin[r];
            z0[r]   = zfin[r];
          }
          float p = __shfl_xor(znext, 1);
          if ((lr & 9) == 0)
            *(uint32_t*)&X[4*lk + r][8*w + lc] = cvt_pk_bf16(znext, p);
        }
      }
      __syncthreads();
    }
  }

  // ---- readout: stage z0 (fp32) into H1-as-float, then dot W_read ----
  float* ZF = (float*)&H1[0][0];   // [16][68] floats (same bytes)
  #pragma unroll
  for (int r = 0; r < 4; ++r)
    if (hp == 0) ZF[(4*lk + r)*68 + h_own] = z0[r];
  __syncthreads();
  if (tid < 16) {
    float acc = b_read[0];
    for (int h = 0; h < 64; ++h) acc = fmaf(ZF[tid*68 + h], W_read[h], acc);
    out[b0 + tid] = acc;
  }
}

extern "C" void kernel_launch(void* const* d_in, const int* in_sizes, int n_in,
                              void* d_out, int out_size, void* d_ws, size_t ws_size,
                              hipStream_t stream) {
  const float* coeffs = (const float*)d_in[0];
  const float* W_init = (const float*)d_in[1];
  const float* b_init = (const float*)d_in[2];
  const float* W_in   = (const float*)d_in[3];
  const float* b_in   = (const float*)d_in[4];
  const float* W_h    = (const float*)d_in[5];
  const float* b_h    = (const float*)d_in[6];
  const float* W_out  = (const float*)d_in[7];
  const float* b_out  = (const float*)d_in[8];
  const float* W_read = (const float*)d_in[9];
  const float* b_read = (const float*)d_in[10];
  float* out = (float*)d_out;

  cde_kernel<<<dim3(256), dim3(512), 0, stream>>>(
      coeffs, W_init, b_init, W_in, b_in, W_h, b_h, W_out, b_out,
      W_read, b_read, out);
}

// Round 4
// 3605.444 us; speedup vs baseline: 2.0147x; 1.2043x over previous
//
#include <hip/hip_runtime.h>
#include <stdint.h>

typedef short s16x8 __attribute__((ext_vector_type(8)));
typedef float f32x4 __attribute__((ext_vector_type(4)));

#define LSEG 511

static __device__ __forceinline__ uint32_t cvt_pk_bf16(float lo, float hi) {
  uint32_t r;
  asm("v_cvt_pk_bf16_f32 %0, %1, %2" : "=v"(r) : "v"(lo), "v"(hi));
  return r;
}
static __device__ __forceinline__ unsigned short f2bf(float f) {
  union { float f; uint32_t u; } v; v.f = f;
  uint32_t r = (v.u + 0x7FFFu + ((v.u >> 16) & 1u)) >> 16;
  return (unsigned short)r;
}
static __device__ __forceinline__ float tanh_fast(float x) {
  float ex = __expf(2.f * x);
  return 1.f - 2.f * __builtin_amdgcn_rcpf(ex + 1.f);
}
// DPP cross-lane (VALU pipe, not DS): xor1 via quad_perm[1,0,3,2]=0xB1,
// xor8-within-16 via row_ror:8=0x128 (i+8 == i-8 mod 16).
static __device__ __forceinline__ float dpp_xor1(float x) {
  return __int_as_float(__builtin_amdgcn_update_dpp(
      0, __float_as_int(x), 0xB1, 0xF, 0xF, false));
}
static __device__ __forceinline__ float dpp_xor8(float x) {
  return __int_as_float(__builtin_amdgcn_update_dpp(
      0, __float_as_int(x), 0x128, 0xF, 0xF, false));
}

// Swizzled LDS tiles (T2): logical [16][128] bf16 rows of 256B (H) and
// [16][64] bf16 rows of 128B (X); 16B block index XOR'd with (row&7).
static __device__ __forceinline__ const s16x8* hread(const char* base, int row, int blk) {
  return (const s16x8*)(base + row*256 + (((blk) ^ (row & 7)) << 4));
}
static __device__ __forceinline__ void hwrite(char* base, int row, int d, uint32_t v) {
  *(uint32_t*)(base + row*256 + (((d << 2) ^ ((row & 7) << 4)))) = v;
}
static __device__ __forceinline__ const s16x8* xread(const char* base, int row, int blk) {
  return (const s16x8*)(base + row*128 + (((blk) ^ (row & 7)) << 4));
}
static __device__ __forceinline__ void xwrite(char* base, int row, int d, uint32_t v) {
  *(uint32_t*)(base + row*128 + (((d << 2) ^ ((row & 7) << 4)))) = v;
}

// 16 batch rows/block, 8 waves. Weights in registers. 4 phases/RK-stage:
// [P1: X->H1] [P2: H1->H2] [P3: H2->H1] [P4: H1 -> f -> einsum -> RK regs -> X]
// RK state (z0, zfin, k1, k2) in einsum-holder lane registers via c-major
// W_out column permutation (ch = 64w + 8*lc + 2*nt + hp). All activation LDS
// XOR-swizzled; all cross-lane via DPP.
__global__ __launch_bounds__(512, 2) void cde_kernel(
    const float* __restrict__ coeffs,
    const float* __restrict__ W_init, const float* __restrict__ b_init,
    const float* __restrict__ W_in,  const float* __restrict__ b_in,
    const float* __restrict__ W_h,   const float* __restrict__ b_h,
    const float* __restrict__ W_out, const float* __restrict__ b_out,
    const float* __restrict__ W_read,const float* __restrict__ b_read,
    float* __restrict__ out)
{
  __shared__ __align__(16) char H1mem[16 * 256];
  __shared__ __align__(16) char H2mem[16 * 256];
  __shared__ __align__(16) char Xmem[16 * 128];
  __shared__ float dx2[4][2][16][4];      // [s][hp][row][nt], c = 2*nt+hp

  const int tid  = threadIdx.x;
  const int w    = tid >> 6;     // wave 0..7
  const int lane = tid & 63;
  const int lr   = lane & 15;
  const int lk   = lane >> 4;
  const int lc   = lr & 7;
  const int hp   = lr >> 3;
  const int b0   = blockIdx.x * 16;
  const int h_own = 8*w + lc;    // this lane's h in the einsum

  // ---- weight fragments (B layout: elem e = W[32*kq+8*lk+e][col]) ----
  s16x8 Win_f[2], Wh0_f[4], Wh1_f[4], Wout_f[4][4];
  const int wc = 16*w + lr;      // L1-3 col
  #pragma unroll
  for (int kq = 0; kq < 2; ++kq)
    #pragma unroll
    for (int e = 0; e < 8; ++e)
      Win_f[kq][e] = (short)f2bf(W_in[(32*kq + 8*lk + e)*128 + wc]);
  #pragma unroll
  for (int kq = 0; kq < 4; ++kq)
    #pragma unroll
    for (int e = 0; e < 8; ++e) {
      Wh0_f[kq][e] = (short)f2bf(W_h[(32*kq + 8*lk + e)*128 + wc]);
      Wh1_f[kq][e] = (short)f2bf(W_h[16384 + (32*kq + 8*lk + e)*128 + wc]);
    }
  #pragma unroll
  for (int kq = 0; kq < 4; ++kq)
    #pragma unroll
    for (int nt = 0; nt < 4; ++nt) {
      const int ch = 64*w + 8*lc + 2*nt + hp;   // c-major permutation
      #pragma unroll
      for (int e = 0; e < 8; ++e)
        Wout_f[kq][nt][e] = (short)f2bf(W_out[(32*kq + 8*lk + e)*512 + ch]);
    }
  const float bin  = b_in[wc];
  const float bh0v = b_h[wc];
  const float bh1v = b_h[128 + wc];
  float bout[4];
  #pragma unroll
  for (int nt = 0; nt < 4; ++nt) bout[nt] = b_out[64*w + 8*lc + 2*nt + hp];

  // ---- z0 init (per-lane registers, 4 rows x 1 h each) ----
  float z0[4], zfin[4], k1r[4], k2r[4];
  {
    float Wi[8];
    #pragma unroll
    for (int c = 0; c < 8; ++c) Wi[c] = W_init[c*64 + h_own];
    const float bi = b_init[h_own];
    #pragma unroll
    for (int r = 0; r < 4; ++r) {
      const float* a0r = &coeffs[(size_t)(b0 + 4*lk + r) * (LSEG*32)];
      float s = bi;
      #pragma unroll
      for (int c = 0; c < 8; ++c) s = fmaf(a0r[c], Wi[c], s);
      z0[r] = s; zfin[r] = 0.f; k1r[r] = 0.f; k2r[r] = 0.f;
    }
    #pragma unroll
    for (int r = 0; r < 4; ++r) {   // X = bf16(z0)
      float p = dpp_xor1(z0[r]);
      if ((lr & 9) == 0)   // lc even, hp==0
        xwrite(Xmem, 4*lk + r, 4*w + (lc >> 1), cvt_pk_bf16(z0[r], p));
    }
  }

  // coeff regs for segment 0
  float cf_b = 0.f, cf_c = 0.f, cf_d = 0.f;
  const int crow = tid >> 3, cc = tid & 7;
  if (tid < 128) {
    const float* cp = &coeffs[(size_t)(b0 + crow)*(LSEG*32)];
    cf_b = cp[8+cc]; cf_c = cp[16+cc]; cf_d = cp[24+cc];
  }
  __syncthreads();

  for (int t = 0; t < LSEG; ++t) {
    #pragma unroll
    for (int s = 0; s < 4; ++s) {
      // =============== P1: (dx2 @ s==0) + L1: X -> H1 ===============
      if (s == 0 && tid < 128) {
        const float third = 1.f/3.f, two3 = 2.f/3.f;
        dx2[0][cc&1][crow][cc>>1] = cf_b;
        dx2[1][cc&1][crow][cc>>1] = fmaf(fmaf(cf_d, third, cf_c), third, cf_b);
        dx2[2][cc&1][crow][cc>>1] = fmaf(fmaf(cf_d, two3, cf_c), two3, cf_b);
        dx2[3][cc&1][crow][cc>>1] = cf_b + cf_c + cf_d;
        if (t + 1 < LSEG) {
          const float* cp = &coeffs[((size_t)(b0 + crow)*LSEG + (t+1))*32];
          cf_b = cp[8+cc]; cf_c = cp[16+cc]; cf_d = cp[24+cc];
        }
      }
      {
        s16x8 a0 = *xread(Xmem, lr, lk);
        s16x8 a1 = *xread(Xmem, lr, 4 + lk);
        f32x4 acc = {};
        acc = __builtin_amdgcn_mfma_f32_16x16x32_bf16(a0, Win_f[0], acc, 0, 0, 0);
        acc = __builtin_amdgcn_mfma_f32_16x16x32_bf16(a1, Win_f[1], acc, 0, 0, 0);
        #pragma unroll
        for (int r = 0; r < 4; ++r) {
          float v = fmaxf(acc[r] + bin, 0.f);
          float p = dpp_xor1(v);
          if ((lr & 1) == 0)
            hwrite(H1mem, 4*lk + r, 8*w + (lr >> 1), cvt_pk_bf16(v, p));
        }
      }
      __syncthreads();

      // =============== P2: L2: H1 -> H2 ===============
      {
        s16x8 a[4];
        #pragma unroll
        for (int kq = 0; kq < 4; ++kq)
          a[kq] = *hread(H1mem, lr, 4*kq + lk);
        f32x4 acc0 = {}, acc1 = {};
        acc0 = __builtin_amdgcn_mfma_f32_16x16x32_bf16(a[0], Wh0_f[0], acc0, 0, 0, 0);
        acc1 = __builtin_amdgcn_mfma_f32_16x16x32_bf16(a[1], Wh0_f[1], acc1, 0, 0, 0);
        acc0 = __builtin_amdgcn_mfma_f32_16x16x32_bf16(a[2], Wh0_f[2], acc0, 0, 0, 0);
        acc1 = __builtin_amdgcn_mfma_f32_16x16x32_bf16(a[3], Wh0_f[3], acc1, 0, 0, 0);
        f32x4 acc = acc0 + acc1;
        #pragma unroll
        for (int r = 0; r < 4; ++r) {
          float v = fmaxf(acc[r] + bh0v, 0.f);
          float p = dpp_xor1(v);
          if ((lr & 1) == 0)
            hwrite(H2mem, 4*lk + r, 8*w + (lr >> 1), cvt_pk_bf16(v, p));
        }
      }
      __syncthreads();

      // =============== P3: L3: H2 -> H1 ===============
      {
        s16x8 a[4];
        #pragma unroll
        for (int kq = 0; kq < 4; ++kq)
          a[kq] = *hread(H2mem, lr, 4*kq + lk);
        f32x4 acc0 = {}, acc1 = {};
        acc0 = __builtin_amdgcn_mfma_f32_16x16x32_bf16(a[0], Wh1_f[0], acc0, 0, 0, 0);
        acc1 = __builtin_amdgcn_mfma_f32_16x16x32_bf16(a[1], Wh1_f[1], acc1, 0, 0, 0);
        acc0 = __builtin_amdgcn_mfma_f32_16x16x32_bf16(a[2], Wh1_f[2], acc0, 0, 0, 0);
        acc1 = __builtin_amdgcn_mfma_f32_16x16x32_bf16(a[3], Wh1_f[3], acc1, 0, 0, 0);
        f32x4 acc = acc0 + acc1;
        #pragma unroll
        for (int r = 0; r < 4; ++r) {
          float v = fmaxf(acc[r] + bh1v, 0.f);
          float p = dpp_xor1(v);
          if ((lr & 1) == 0)
            hwrite(H1mem, 4*lk + r, 8*w + (lr >> 1), cvt_pk_bf16(v, p));
        }
      }
      __syncthreads();

      // ========= P4: L4 + tanh + einsum + RK state + X write =========
      {
        s16x8 a[4];
        #pragma unroll
        for (int kq = 0; kq < 4; ++kq)
          a[kq] = *hread(H1mem, lr, 4*kq + lk);
        f32x4 acc[4] = {};
        #pragma unroll
        for (int kq = 0; kq < 4; ++kq)
          #pragma unroll
          for (int nt = 0; nt < 4; ++nt)
            acc[nt] = __builtin_amdgcn_mfma_f32_16x16x32_bf16(a[kq], Wout_f[kq][nt], acc[nt], 0, 0, 0);
        #pragma unroll
        for (int r = 0; r < 4; ++r) {
          f32x4 dxv = *(const f32x4*)&dx2[s][hp][4*lk + r][0];
          float sum = 0.f;
          #pragma unroll
          for (int nt = 0; nt < 4; ++nt)
            sum = fmaf(tanh_fast(acc[nt][r] + bout[nt]), dxv[nt], sum);
          sum += dpp_xor8(sum);        // add hp-complement: full c-sum
          float znext;
          if (s == 0) {
            k1r[r] = sum;
            zfin[r] = fmaf(0.125f, sum, z0[r]);
            znext   = fmaf(1.f/3.f, sum, z0[r]);
          } else if (s == 1) {
            k2r[r] = sum;
            zfin[r] = fmaf(0.375f, sum, zfin[r]);
            znext   = z0[r] + sum - (1.f/3.f)*k1r[r];
          } else if (s == 2) {
            zfin[r] = fmaf(0.375f, sum, zfin[r]);
            znext   = z0[r] + k1r[r] - k2r[r] + sum;
          } else {
            zfin[r] = fmaf(0.125f, sum, zfin[r]);
            znext   = zfin[r];
            z0[r]   = zfin[r];
          }
          float p = dpp_xor1(znext);
          if ((lr & 9) == 0)
            xwrite(Xmem, 4*lk + r, 4*w + (lc >> 1), cvt_pk_bf16(znext, p));
        }
      }
      __syncthreads();
    }
  }

  // ---- readout: stage z0 (fp32) into H1 bytes, then dot W_read ----
  float* ZF = (float*)H1mem;   // plain [16][64] floats
  #pragma unroll
  for (int r = 0; r < 4; ++r)
    if (hp == 0) ZF[(4*lk + r)*64 + h_own] = z0[r];
  __syncthreads();
  if (tid < 16) {
    float acc = b_read[0];
    for (int h = 0; h < 64; ++h) acc = fmaf(ZF[tid*64 + h], W_read[h], acc);
    out[b0 + tid] = acc;
  }
}

extern "C" void kernel_launch(void* const* d_in, const int* in_sizes, int n_in,
                              void* d_out, int out_size, void* d_ws, size_t ws_size,
                              hipStream_t stream) {
  const float* coeffs = (const float*)d_in[0];
  const float* W_init = (const float*)d_in[1];
  const float* b_init = (const float*)d_in[2];
  const float* W_in   = (const float*)d_in[3];
  const float* b_in   = (const float*)d_in[4];
  const float* W_h    = (const float*)d_in[5];
  const float* b_h    = (const float*)d_in[6];
  const float* W_out  = (const float*)d_in[7];
  const float* b_out  = (const float*)d_in[8];
  const float* W_read = (const float*)d_in[9];
  const float* b_read = (const float*)d_in[10];
  float* out = (float*)d_out;

  cde_kernel<<<dim3(256), dim3(512), 0, stream>>>(
      coeffs, W_init, b_init, W_in, b_in, W_h, b_h, W_out, b_out,
      W_read, b_read, out);
}

// Round 5
// 2999.440 us; speedup vs baseline: 2.4217x; 1.2020x over previous
//
#include <hip/hip_runtime.h>
#include <stdint.h>

typedef short s16x8 __attribute__((ext_vector_type(8)));
typedef float f32x4 __attribute__((ext_vector_type(4)));

#define LSEG 511

static __device__ __forceinline__ uint32_t cvt_pk_bf16(float lo, float hi) {
  uint32_t r;
  asm("v_cvt_pk_bf16_f32 %0, %1, %2" : "=v"(r) : "v"(lo), "v"(hi));
  return r;
}
static __device__ __forceinline__ unsigned short f2bf(float f) {
  union { float f; uint32_t u; } v; v.f = f;
  uint32_t r = (v.u + 0x7FFFu + ((v.u >> 16) & 1u)) >> 16;
  return (unsigned short)r;
}
static __device__ __forceinline__ float tanh_fast(float x) {
  float ex = __expf(2.f * x);
  return 1.f - 2.f * __builtin_amdgcn_rcpf(ex + 1.f);
}
// DPP cross-lane: xor8 within 16 lanes via row_ror:8 (i^8 == (i+8) mod 16).
static __device__ __forceinline__ float dpp_xor8(float x) {
  return __int_as_float(__builtin_amdgcn_update_dpp(
      0, __float_as_int(x), 0x128, 0xF, 0xF, false));
}

// Swizzled LDS tiles (T2): H rows are 256B (16 blocks of 16B), X rows 128B.
// Physical 16B-block index = logical ^ (row & 7).
static __device__ __forceinline__ const s16x8* hread(const char* base, int row, int blk) {
  return (const s16x8*)(base + row*256 + (((blk) ^ (row & 7)) << 4));
}
static __device__ __forceinline__ void hwrite16(char* base, int row, int col, unsigned short v) {
  const int byte = ((((col >> 3) ^ (row & 7)) << 4) | ((col & 7) << 1));
  *(unsigned short*)(base + row*256 + byte) = v;
}
static __device__ __forceinline__ const s16x8* xread(const char* base, int row, int blk) {
  return (const s16x8*)(base + row*128 + (((blk) ^ (row & 7)) << 4));
}
static __device__ __forceinline__ void xwrite16(char* base, int row, int col, unsigned short v) {
  const int byte = ((((col >> 3) ^ (row & 7)) << 4) | ((col & 7) << 1));
  *(unsigned short*)(base + row*128 + byte) = v;
}

// 16 batch rows/block, 8 waves, 1 block/CU (2 waves/SIMD — declared via
// waves_per_eu(2,2) so the compiler uses the full 256-VGPR budget and hoists
// loop-invariant LDS addresses instead of rematerializing).
// Per RK stage 4 phases/barriers:
// [P1: X->H1] [P2: H1->H2] [P3: H2->H1] [P4: H1 -> f -> einsum -> RK -> X]
// RK state in einsum-holder lane registers (c-major W_out permutation).
// Biases folded into MFMA C-in. Epilogues: per-lane cvt_pk + ds_write_b16.
__global__ __attribute__((amdgpu_flat_work_group_size(512, 512),
                          amdgpu_waves_per_eu(2, 2)))
void cde_kernel(
    const float* __restrict__ coeffs,
    const float* __restrict__ W_init, const float* __restrict__ b_init,
    const float* __restrict__ W_in,  const float* __restrict__ b_in,
    const float* __restrict__ W_h,   const float* __restrict__ b_h,
    const float* __restrict__ W_out, const float* __restrict__ b_out,
    const float* __restrict__ W_read,const float* __restrict__ b_read,
    float* __restrict__ out)
{
  __shared__ __align__(16) char H1mem[16 * 256];
  __shared__ __align__(16) char H2mem[16 * 256];
  __shared__ __align__(16) char Xmem[16 * 128];
  __shared__ float dx2[4][2][16][4];      // [s][hp][row][nt], c = 2*nt+hp

  const int tid  = threadIdx.x;
  const int w    = tid >> 6;     // wave 0..7
  const int lane = tid & 63;
  const int lr   = lane & 15;
  const int lk   = lane >> 4;
  const int lc   = lr & 7;
  const int hp   = lr >> 3;
  const int b0   = blockIdx.x * 16;
  const int h_own = 8*w + lc;    // this lane's h in the einsum

  // ---- weight fragments (B layout: elem e = W[32*kq+8*lk+e][col]) ----
  s16x8 Win_f[2], Wh0_f[4], Wh1_f[4], Wout_f[4][4];
  const int wc = 16*w + lr;      // L1-3 col
  #pragma unroll
  for (int kq = 0; kq < 2; ++kq)
    #pragma unroll
    for (int e = 0; e < 8; ++e)
      Win_f[kq][e] = (short)f2bf(W_in[(32*kq + 8*lk + e)*128 + wc]);
  #pragma unroll
  for (int kq = 0; kq < 4; ++kq)
    #pragma unroll
    for (int e = 0; e < 8; ++e) {
      Wh0_f[kq][e] = (short)f2bf(W_h[(32*kq + 8*lk + e)*128 + wc]);
      Wh1_f[kq][e] = (short)f2bf(W_h[16384 + (32*kq + 8*lk + e)*128 + wc]);
    }
  #pragma unroll
  for (int kq = 0; kq < 4; ++kq)
    #pragma unroll
    for (int nt = 0; nt < 4; ++nt) {
      const int ch = 64*w + 8*lc + 2*nt + hp;   // c-major permutation
      #pragma unroll
      for (int e = 0; e < 8; ++e)
        Wout_f[kq][nt][e] = (short)f2bf(W_out[(32*kq + 8*lk + e)*512 + ch]);
    }
  // bias splats for MFMA C-in folding (hoisted, loop-invariant)
  const float binv = b_in[wc];
  const float bh0v = b_h[wc];
  const float bh1v = b_h[128 + wc];
  const f32x4 bin4 = {binv, binv, binv, binv};
  const f32x4 bh04 = {bh0v, bh0v, bh0v, bh0v};
  const f32x4 bh14 = {bh1v, bh1v, bh1v, bh1v};
  f32x4 bout4[4];
  #pragma unroll
  for (int nt = 0; nt < 4; ++nt) {
    const float b = b_out[64*w + 8*lc + 2*nt + hp];
    bout4[nt] = (f32x4){b, b, b, b};
  }

  // ---- z0 init (per-lane registers, 4 rows x 1 h each) ----
  float z0[4], zfin[4], k1r[4], k2r[4];
  {
    float Wi[8];
    #pragma unroll
    for (int c = 0; c < 8; ++c) Wi[c] = W_init[c*64 + h_own];
    const float bi = b_init[h_own];
    #pragma unroll
    for (int r = 0; r < 4; ++r) {
      const float* a0r = &coeffs[(size_t)(b0 + 4*lk + r) * (LSEG*32)];
      float s = bi;
      #pragma unroll
      for (int c = 0; c < 8; ++c) s = fmaf(a0r[c], Wi[c], s);
      z0[r] = s; zfin[r] = 0.f; k1r[r] = 0.f; k2r[r] = 0.f;
    }
    #pragma unroll
    for (int r = 0; r < 4; ++r)
      if (hp == 0)
        xwrite16(Xmem, 4*lk + r, h_own, (unsigned short)cvt_pk_bf16(z0[r], z0[r]));
  }

  // coeff regs for segment 0
  float cf_b = 0.f, cf_c = 0.f, cf_d = 0.f;
  const int crow = tid >> 3, cc = tid & 7;
  if (tid < 128) {
    const float* cp = &coeffs[(size_t)(b0 + crow)*(LSEG*32)];
    cf_b = cp[8+cc]; cf_c = cp[16+cc]; cf_d = cp[24+cc];
  }
  __syncthreads();

  for (int t = 0; t < LSEG; ++t) {
    #pragma unroll
    for (int s = 0; s < 4; ++s) {
      // =============== P1: (dx2 @ s==0) + L1: X -> H1 ===============
      if (s == 0 && tid < 128) {
        const float third = 1.f/3.f, two3 = 2.f/3.f;
        dx2[0][cc&1][crow][cc>>1] = cf_b;
        dx2[1][cc&1][crow][cc>>1] = fmaf(fmaf(cf_d, third, cf_c), third, cf_b);
        dx2[2][cc&1][crow][cc>>1] = fmaf(fmaf(cf_d, two3, cf_c), two3, cf_b);
        dx2[3][cc&1][crow][cc>>1] = cf_b + cf_c + cf_d;
        if (t + 1 < LSEG) {
          const float* cp = &coeffs[((size_t)(b0 + crow)*LSEG + (t+1))*32];
          cf_b = cp[8+cc]; cf_c = cp[16+cc]; cf_d = cp[24+cc];
        }
      }
      {
        s16x8 a0 = *xread(Xmem, lr, lk);
        s16x8 a1 = *xread(Xmem, lr, 4 + lk);
        f32x4 acc;
        acc = __builtin_amdgcn_mfma_f32_16x16x32_bf16(a0, Win_f[0], bin4, 0, 0, 0);
        acc = __builtin_amdgcn_mfma_f32_16x16x32_bf16(a1, Win_f[1], acc, 0, 0, 0);
        #pragma unroll
        for (int r = 0; r < 4; ++r) {
          float v = fmaxf(acc[r], 0.f);
          hwrite16(H1mem, 4*lk + r, wc, (unsigned short)cvt_pk_bf16(v, v));
        }
      }
      __syncthreads();

      // =============== P2: L2: H1 -> H2 ===============
      {
        s16x8 a[4];
        #pragma unroll
        for (int kq = 0; kq < 4; ++kq)
          a[kq] = *hread(H1mem, lr, 4*kq + lk);
        f32x4 acc0, acc1 = {};
        acc0 = __builtin_amdgcn_mfma_f32_16x16x32_bf16(a[0], Wh0_f[0], bh04, 0, 0, 0);
        acc1 = __builtin_amdgcn_mfma_f32_16x16x32_bf16(a[1], Wh0_f[1], acc1, 0, 0, 0);
        acc0 = __builtin_amdgcn_mfma_f32_16x16x32_bf16(a[2], Wh0_f[2], acc0, 0, 0, 0);
        acc1 = __builtin_amdgcn_mfma_f32_16x16x32_bf16(a[3], Wh0_f[3], acc1, 0, 0, 0);
        f32x4 acc = acc0 + acc1;
        #pragma unroll
        for (int r = 0; r < 4; ++r) {
          float v = fmaxf(acc[r], 0.f);
          hwrite16(H2mem, 4*lk + r, wc, (unsigned short)cvt_pk_bf16(v, v));
        }
      }
      __syncthreads();

      // =============== P3: L3: H2 -> H1 ===============
      {
        s16x8 a[4];
        #pragma unroll
        for (int kq = 0; kq < 4; ++kq)
          a[kq] = *hread(H2mem, lr, 4*kq + lk);
        f32x4 acc0, acc1 = {};
        acc0 = __builtin_amdgcn_mfma_f32_16x16x32_bf16(a[0], Wh1_f[0], bh14, 0, 0, 0);
        acc1 = __builtin_amdgcn_mfma_f32_16x16x32_bf16(a[1], Wh1_f[1], acc1, 0, 0, 0);
        acc0 = __builtin_amdgcn_mfma_f32_16x16x32_bf16(a[2], Wh1_f[2], acc0, 0, 0, 0);
        acc1 = __builtin_amdgcn_mfma_f32_16x16x32_bf16(a[3], Wh1_f[3], acc1, 0, 0, 0);
        f32x4 acc = acc0 + acc1;
        #pragma unroll
        for (int r = 0; r < 4; ++r) {
          float v = fmaxf(acc[r], 0.f);
          hwrite16(H1mem, 4*lk + r, wc, (unsigned short)cvt_pk_bf16(v, v));
        }
      }
      __syncthreads();

      // ========= P4: L4 + tanh + einsum + RK state + X write =========
      {
        // issue dx reads first (independent of the MFMAs)
        f32x4 dxv[4];
        #pragma unroll
        for (int r = 0; r < 4; ++r)
          dxv[r] = *(const f32x4*)&dx2[s][hp][4*lk + r][0];
        s16x8 a[4];
        #pragma unroll
        for (int kq = 0; kq < 4; ++kq)
          a[kq] = *hread(H1mem, lr, 4*kq + lk);
        f32x4 acc[4];
        #pragma unroll
        for (int nt = 0; nt < 4; ++nt)
          acc[nt] = __builtin_amdgcn_mfma_f32_16x16x32_bf16(a[0], Wout_f[0][nt], bout4[nt], 0, 0, 0);
        #pragma unroll
        for (int kq = 1; kq < 4; ++kq)
          #pragma unroll
          for (int nt = 0; nt < 4; ++nt)
            acc[nt] = __builtin_amdgcn_mfma_f32_16x16x32_bf16(a[kq], Wout_f[kq][nt], acc[nt], 0, 0, 0);
        #pragma unroll
        for (int r = 0; r < 4; ++r) {
          float sum = 0.f;
          #pragma unroll
          for (int nt = 0; nt < 4; ++nt)
            sum = fmaf(tanh_fast(acc[nt][r]), dxv[r][nt], sum);
          sum += dpp_xor8(sum);        // add hp-complement: full c-sum
          float znext;
          if (s == 0) {
            k1r[r] = sum;
            zfin[r] = fmaf(0.125f, sum, z0[r]);
            znext   = fmaf(1.f/3.f, sum, z0[r]);
          } else if (s == 1) {
            k2r[r] = sum;
            zfin[r] = fmaf(0.375f, sum, zfin[r]);
            znext   = z0[r] + sum - (1.f/3.f)*k1r[r];
          } else if (s == 2) {
            zfin[r] = fmaf(0.375f, sum, zfin[r]);
            znext   = z0[r] + k1r[r] - k2r[r] + sum;
          } else {
            zfin[r] = fmaf(0.125f, sum, zfin[r]);
            znext   = zfin[r];
            z0[r]   = zfin[r];
          }
          if (hp == 0)
            xwrite16(Xmem, 4*lk + r, h_own, (unsigned short)cvt_pk_bf16(znext, znext));
        }
      }
      __syncthreads();
    }
  }

  // ---- readout: stage z0 (fp32) into H1 bytes, then dot W_read ----
  float* ZF = (float*)H1mem;   // plain [16][64] floats
  #pragma unroll
  for (int r = 0; r < 4; ++r)
    if (hp == 0) ZF[(4*lk + r)*64 + h_own] = z0[r];
  __syncthreads();
  if (tid < 16) {
    float acc = b_read[0];
    for (int h = 0; h < 64; ++h) acc = fmaf(ZF[tid*64 + h], W_read[h], acc);
    out[b0 + tid] = acc;
  }
}

extern "C" void kernel_launch(void* const* d_in, const int* in_sizes, int n_in,
                              void* d_out, int out_size, void* d_ws, size_t ws_size,
                              hipStream_t stream) {
  const float* coeffs = (const float*)d_in[0];
  const float* W_init = (const float*)d_in[1];
  const float* b_init = (const float*)d_in[2];
  const float* W_in   = (const float*)d_in[3];
  const float* b_in   = (const float*)d_in[4];
  const float* W_h    = (const float*)d_in[5];
  const float* b_h    = (const float*)d_in[6];
  const float* W_out  = (const float*)d_in[7];
  const float* b_out  = (const float*)d_in[8];
  const float* W_read = (const float*)d_in[9];
  const float* b_read = (const float*)d_in[10];
  float* out = (float*)d_out;

  cde_kernel<<<dim3(256), dim3(512), 0, stream>>>(
      coeffs, W_init, b_init, W_in, b_in, W_h, b_h, W_out, b_out,
      W_read, b_read, out);
}

// Round 6
// 2987.873 us; speedup vs baseline: 2.4311x; 1.0039x over previous
//
#include <hip/hip_runtime.h>
#include <stdint.h>

typedef short s16x8 __attribute__((ext_vector_type(8)));
typedef float f32x4 __attribute__((ext_vector_type(4)));

#define LSEG 511

static __device__ __forceinline__ uint32_t cvt_pk_bf16(float lo, float hi) {
  uint32_t r;
  asm("v_cvt_pk_bf16_f32 %0, %1, %2" : "=v"(r) : "v"(lo), "v"(hi));
  return r;
}
static __device__ __forceinline__ unsigned short f2bf(float f) {
  union { float f; uint32_t u; } v; v.f = f;
  uint32_t r = (v.u + 0x7FFFu + ((v.u >> 16) & 1u)) >> 16;
  return (unsigned short)r;
}
static __device__ __forceinline__ float tanh_fast(float x) {
  float ex = __expf(2.f * x);
  return 1.f - 2.f * __builtin_amdgcn_rcpf(ex + 1.f);
}
// DPP cross-lane: xor8 within 16 lanes via row_ror:8 (i^8 == (i+8) mod 16).
static __device__ __forceinline__ float dpp_xor8(float x) {
  return __int_as_float(__builtin_amdgcn_update_dpp(
      0, __float_as_int(x), 0x128, 0xF, 0xF, false));
}

// 16 batch rows/block, 8 waves, 1 block/CU (2 waves/SIMD).
// XOR-swizzled LDS (phys 16B-block = logical ^ (row&7)), but ALL addresses
// are precomputed per-lane base registers + compile-time immediates:
//   H read  kq=0..3: {vbHe+0, vbHo+0, vbHe+128, vbHo+128} (+ buffer const)
//   X read  a0/a1:   vbX0 / vbX1 (= vbX0 ^ 64, precomputed)
//   writes: per-row invariant byte offsets wbH[r] / wbX[j]
// RK state hp-split: each lane owns rows 4lk+2hp+{0,1} (state/write halved;
// after dpp_xor8 both halves hold full sums).
__global__ __attribute__((amdgpu_flat_work_group_size(512, 512),
                          amdgpu_waves_per_eu(2, 2)))
void cde_kernel(
    const float* __restrict__ coeffs,
    const float* __restrict__ W_init, const float* __restrict__ b_init,
    const float* __restrict__ W_in,  const float* __restrict__ b_in,
    const float* __restrict__ W_h,   const float* __restrict__ b_h,
    const float* __restrict__ W_out, const float* __restrict__ b_out,
    const float* __restrict__ W_read,const float* __restrict__ b_read,
    float* __restrict__ out)
{
  __shared__ __align__(16) char H1mem[16 * 256];
  __shared__ __align__(16) char H2mem[16 * 256];
  __shared__ __align__(16) char Xmem[16 * 128];
  __shared__ float dx2[4][2][16][4];      // [s][hp][row][nt], c = 2*nt+hp

  const int tid  = threadIdx.x;
  const int w    = tid >> 6;     // wave 0..7
  const int lane = tid & 63;
  const int lr   = lane & 15;
  const int lk   = lane >> 4;
  const int lc   = lr & 7;
  const int hp   = lr >> 3;
  const int b0   = blockIdx.x * 16;
  const int h_own = 8*w + lc;    // this lane's h in the einsum

  // ---- weight fragments (B layout: elem e = W[32*kq+8*lk+e][col]) ----
  s16x8 Win_f[2], Wh0_f[4], Wh1_f[4], Wout_f[4][4];
  const int wc = 16*w + lr;      // L1-3 col
  #pragma unroll
  for (int kq = 0; kq < 2; ++kq)
    #pragma unroll
    for (int e = 0; e < 8; ++e)
      Win_f[kq][e] = (short)f2bf(W_in[(32*kq + 8*lk + e)*128 + wc]);
  #pragma unroll
  for (int kq = 0; kq < 4; ++kq)
    #pragma unroll
    for (int e = 0; e < 8; ++e) {
      Wh0_f[kq][e] = (short)f2bf(W_h[(32*kq + 8*lk + e)*128 + wc]);
      Wh1_f[kq][e] = (short)f2bf(W_h[16384 + (32*kq + 8*lk + e)*128 + wc]);
    }
  #pragma unroll
  for (int kq = 0; kq < 4; ++kq)
    #pragma unroll
    for (int nt = 0; nt < 4; ++nt) {
      const int ch = 64*w + 8*lc + 2*nt + hp;   // c-major permutation
      #pragma unroll
      for (int e = 0; e < 8; ++e)
        Wout_f[kq][nt][e] = (short)f2bf(W_out[(32*kq + 8*lk + e)*512 + ch]);
    }
  // bias splats for MFMA C-in folding
  const float binv = b_in[wc];
  const float bh0v = b_h[wc];
  const float bh1v = b_h[128 + wc];
  const f32x4 bin4 = {binv, binv, binv, binv};
  const f32x4 bh04 = {bh0v, bh0v, bh0v, bh0v};
  const f32x4 bh14 = {bh1v, bh1v, bh1v, bh1v};
  f32x4 bout4[4];
  #pragma unroll
  for (int nt = 0; nt < 4; ++nt) {
    const float b = b_out[64*w + 8*lc + 2*nt + hp];
    bout4[nt] = (f32x4){b, b, b, b};
  }

  // ---- precomputed LDS byte offsets (loop-invariant per lane) ----
  const int r2  = (lr >> 2) & 1;
  const int vbHe = lr*256 + (((lk ^ lr) & 3) << 4) + (r2 << 6);
  const int vbHo = lr*256 + (((lk ^ lr) & 3) << 4) + ((1 ^ r2) << 6);
  const int vbX0 = lr*128 + ((lk ^ (lr & 7)) << 4);
  const int vbX1 = vbX0 ^ 64;
  int wbH[4];
  #pragma unroll
  for (int r = 0; r < 4; ++r) {
    const int row = 4*lk + r;
    wbH[r] = row*256 + ((((2*w + (lr >> 3)) ^ (row & 7)) << 4)) + ((lr & 7) << 1);
  }
  int wbX[2];
  #pragma unroll
  for (int j = 0; j < 2; ++j) {
    const int ro = 4*lk + 2*hp + j;
    wbX[j] = ro*128 + (((w ^ (ro & 7)) << 4)) + (lc << 1);
  }
  const int dbx = hp*256 + (lk << 6);   // dx2 base: + s*512 + r*16

  // ---- z0 init: lane owns rows 4lk+2hp+{0,1}, channel h_own ----
  float z0[2], zfin[2], k1r[2], k2r[2];
  {
    float Wi[8];
    #pragma unroll
    for (int c = 0; c < 8; ++c) Wi[c] = W_init[c*64 + h_own];
    const float bi = b_init[h_own];
    #pragma unroll
    for (int j = 0; j < 2; ++j) {
      const int ro = 4*lk + 2*hp + j;
      const float* a0r = &coeffs[(size_t)(b0 + ro) * (LSEG*32)];
      float s = bi;
      #pragma unroll
      for (int c = 0; c < 8; ++c) s = fmaf(a0r[c], Wi[c], s);
      z0[j] = s; zfin[j] = 0.f; k1r[j] = 0.f; k2r[j] = 0.f;
      *(unsigned short*)(Xmem + wbX[j]) = f2bf(s);
    }
  }

  // coeff regs for segment 0: active lanes (lane&3)==0 handle
  // (crow = 2w + (lane>>5), cc = (lane>>2)&7)
  float cf_b = 0.f, cf_c = 0.f, cf_d = 0.f;
  const int crow = 2*w + (lane >> 5), ccc = (lane >> 2) & 7;
  const bool cact = (lane & 3) == 0;
  if (cact) {
    const float* cp = &coeffs[(size_t)(b0 + crow)*(LSEG*32)];
    cf_b = cp[8+ccc]; cf_c = cp[16+ccc]; cf_d = cp[24+ccc];
  }
  __syncthreads();

  #pragma unroll 1
  for (int t = 0; t < LSEG; ++t) {
    #pragma unroll
    for (int s = 0; s < 4; ++s) {
      // =============== P1: (dx2 @ s==0) + L1: X -> H1 ===============
      if (s == 0 && cact) {
        const float third = 1.f/3.f, two3 = 2.f/3.f;
        const int dxo = (ccc & 1)*256 + crow*16 + (ccc >> 1)*4;
        *(float*)((char*)dx2 + dxo)        = cf_b;
        *(float*)((char*)dx2 + dxo + 512)  = fmaf(fmaf(cf_d, third, cf_c), third, cf_b);
        *(float*)((char*)dx2 + dxo + 1024) = fmaf(fmaf(cf_d, two3, cf_c), two3, cf_b);
        *(float*)((char*)dx2 + dxo + 1536) = cf_b + cf_c + cf_d;
        if (t + 1 < LSEG) {
          const float* cp = &coeffs[((size_t)(b0 + crow)*LSEG + (t+1))*32];
          cf_b = cp[8+ccc]; cf_c = cp[16+ccc]; cf_d = cp[24+ccc];
        }
      }
      {
        s16x8 a0 = *(const s16x8*)(Xmem + vbX0);
        s16x8 a1 = *(const s16x8*)(Xmem + vbX1);
        f32x4 acc;
        acc = __builtin_amdgcn_mfma_f32_16x16x32_bf16(a0, Win_f[0], bin4, 0, 0, 0);
        acc = __builtin_amdgcn_mfma_f32_16x16x32_bf16(a1, Win_f[1], acc, 0, 0, 0);
        #pragma unroll
        for (int r = 0; r < 4; ++r) {
          float v = fmaxf(acc[r], 0.f);
          *(unsigned short*)(H1mem + wbH[r]) = (unsigned short)cvt_pk_bf16(v, v);
        }
      }
      __syncthreads();

      // =============== P2: L2: H1 -> H2 ===============
      {
        s16x8 a0 = *(const s16x8*)(H1mem + vbHe);
        s16x8 a1 = *(const s16x8*)(H1mem + vbHo);
        s16x8 a2 = *(const s16x8*)(H1mem + vbHe + 128);
        s16x8 a3 = *(const s16x8*)(H1mem + vbHo + 128);
        f32x4 acc0, acc1 = {};
        acc0 = __builtin_amdgcn_mfma_f32_16x16x32_bf16(a0, Wh0_f[0], bh04, 0, 0, 0);
        acc1 = __builtin_amdgcn_mfma_f32_16x16x32_bf16(a1, Wh0_f[1], acc1, 0, 0, 0);
        acc0 = __builtin_amdgcn_mfma_f32_16x16x32_bf16(a2, Wh0_f[2], acc0, 0, 0, 0);
        acc1 = __builtin_amdgcn_mfma_f32_16x16x32_bf16(a3, Wh0_f[3], acc1, 0, 0, 0);
        f32x4 acc = acc0 + acc1;
        #pragma unroll
        for (int r = 0; r < 4; ++r) {
          float v = fmaxf(acc[r], 0.f);
          *(unsigned short*)(H2mem + wbH[r]) = (unsigned short)cvt_pk_bf16(v, v);
        }
      }
      __syncthreads();

      // =============== P3: L3: H2 -> H1 ===============
      {
        s16x8 a0 = *(const s16x8*)(H2mem + vbHe);
        s16x8 a1 = *(const s16x8*)(H2mem + vbHo);
        s16x8 a2 = *(const s16x8*)(H2mem + vbHe + 128);
        s16x8 a3 = *(const s16x8*)(H2mem + vbHo + 128);
        f32x4 acc0, acc1 = {};
        acc0 = __builtin_amdgcn_mfma_f32_16x16x32_bf16(a0, Wh1_f[0], bh14, 0, 0, 0);
        acc1 = __builtin_amdgcn_mfma_f32_16x16x32_bf16(a1, Wh1_f[1], acc1, 0, 0, 0);
        acc0 = __builtin_amdgcn_mfma_f32_16x16x32_bf16(a2, Wh1_f[2], acc0, 0, 0, 0);
        acc1 = __builtin_amdgcn_mfma_f32_16x16x32_bf16(a3, Wh1_f[3], acc1, 0, 0, 0);
        f32x4 acc = acc0 + acc1;
        #pragma unroll
        for (int r = 0; r < 4; ++r) {
          float v = fmaxf(acc[r], 0.f);
          *(unsigned short*)(H1mem + wbH[r]) = (unsigned short)cvt_pk_bf16(v, v);
        }
      }
      __syncthreads();

      // ========= P4: L4 + tanh + einsum + RK state + X write =========
      {
        f32x4 dxv[4];
        #pragma unroll
        for (int r = 0; r < 4; ++r)
          dxv[r] = *(const f32x4*)((char*)dx2 + dbx + s*512 + r*16);
        s16x8 a0 = *(const s16x8*)(H1mem + vbHe);
        s16x8 a1 = *(const s16x8*)(H1mem + vbHo);
        s16x8 a2 = *(const s16x8*)(H1mem + vbHe + 128);
        s16x8 a3 = *(const s16x8*)(H1mem + vbHo + 128);
        f32x4 acc[4];
        #pragma unroll
        for (int nt = 0; nt < 4; ++nt)
          acc[nt] = __builtin_amdgcn_mfma_f32_16x16x32_bf16(a0, Wout_f[0][nt], bout4[nt], 0, 0, 0);
        #pragma unroll
        for (int nt = 0; nt < 4; ++nt)
          acc[nt] = __builtin_amdgcn_mfma_f32_16x16x32_bf16(a1, Wout_f[1][nt], acc[nt], 0, 0, 0);
        #pragma unroll
        for (int nt = 0; nt < 4; ++nt)
          acc[nt] = __builtin_amdgcn_mfma_f32_16x16x32_bf16(a2, Wout_f[2][nt], acc[nt], 0, 0, 0);
        #pragma unroll
        for (int nt = 0; nt < 4; ++nt)
          acc[nt] = __builtin_amdgcn_mfma_f32_16x16x32_bf16(a3, Wout_f[3][nt], acc[nt], 0, 0, 0);
        float sums[4];
        #pragma unroll
        for (int r = 0; r < 4; ++r) {
          float sum = 0.f;
          #pragma unroll
          for (int nt = 0; nt < 4; ++nt)
            sum = fmaf(tanh_fast(acc[nt][r]), dxv[r][nt], sum);
          sums[r] = sum + dpp_xor8(sum);   // full c-sum on both hp halves
        }
        #pragma unroll
        for (int j = 0; j < 2; ++j) {
          const float sum = sums[2*hp + j];
          float znext;
          if (s == 0) {
            k1r[j] = sum;
            zfin[j] = fmaf(0.125f, sum, z0[j]);
            znext   = fmaf(1.f/3.f, sum, z0[j]);
          } else if (s == 1) {
            k2r[j] = sum;
            zfin[j] = fmaf(0.375f, sum, zfin[j]);
            znext   = z0[j] + sum - (1.f/3.f)*k1r[j];
          } else if (s == 2) {
            zfin[j] = fmaf(0.375f, sum, zfin[j]);
            znext   = z0[j] + k1r[j] - k2r[j] + sum;
          } else {
            zfin[j] = fmaf(0.125f, sum, zfin[j]);
            znext   = zfin[j];
            z0[j]   = zfin[j];
          }
          *(unsigned short*)(Xmem + wbX[j]) = (unsigned short)cvt_pk_bf16(znext, znext);
        }
      }
      __syncthreads();
    }
  }

  // ---- readout: stage z0 (fp32) into H1 bytes, then dot W_read ----
  float* ZF = (float*)H1mem;   // plain [16][64] floats
  #pragma unroll
  for (int j = 0; j < 2; ++j)
    ZF[(4*lk + 2*hp + j)*64 + h_own] = z0[j];
  __syncthreads();
  if (tid < 16) {
    float acc = b_read[0];
    for (int h = 0; h < 64; ++h) acc = fmaf(ZF[tid*64 + h], W_read[h], acc);
    out[b0 + tid] = acc;
  }
}

extern "C" void kernel_launch(void* const* d_in, const int* in_sizes, int n_in,
                              void* d_out, int out_size, void* d_ws, size_t ws_size,
                              hipStream_t stream) {
  const float* coeffs = (const float*)d_in[0];
  const float* W_init = (const float*)d_in[1];
  const float* b_init = (const float*)d_in[2];
  const float* W_in   = (const float*)d_in[3];
  const float* b_in   = (const float*)d_in[4];
  const float* W_h    = (const float*)d_in[5];
  const float* b_h    = (const float*)d_in[6];
  const float* W_out  = (const float*)d_in[7];
  const float* b_out  = (const float*)d_in[8];
  const float* W_read = (const float*)d_in[9];
  const float* b_read = (const float*)d_in[10];
  float* out = (float*)d_out;

  cde_kernel<<<dim3(256), dim3(512), 0, stream>>>(
      coeffs, W_init, b_init, W_in, b_in, W_h, b_h, W_out, b_out,
      W_read, b_read, out);
}